// Round 1
// baseline (1564.222 us; speedup 1.0000x reference)
//
#include <hip/hip_runtime.h>
#include <math.h>

// Problem constants (from reference)
#define NROWS 65536      // B*T = 16*4096
#define CDIM 512         // C
#define MDIM 640         // G*V
#define VDIM 320         // NUM_VARS
#define DDIM 128         // codebook dim
#define ROWS 8           // rows per block
#define NREP 64          // replicated global accumulators for avg_probs
#define OUTN (NROWS * 256)  // 16777216 floats for the gather output

__global__ __launch_bounds__(256) void zero_ws_kernel(float* ws, int n) {
  int i = blockIdx.x * 256 + threadIdx.x;
  if (i < n) ws[i] = 0.f;
}

__global__ __launch_bounds__(256) void gvq_main_kernel(
    const float* __restrict__ x, const float* __restrict__ W,
    const float* __restrict__ b, const float* __restrict__ cb,
    float* __restrict__ out, float* __restrict__ ws_avgp,
    float* __restrict__ ws_hist) {
  __shared__ float xs[ROWS][CDIM];   // 16 KB
  __shared__ float lg[ROWS][MDIM];   // 20 KB
  __shared__ float avgp[MDIM];       // 2.5 KB
  __shared__ int rowk[ROWS][2];

  const int t = threadIdx.x;
  const int row0 = blockIdx.x * ROWS;

  // zero the per-block avg_probs accumulator
  avgp[t] = 0.f;
  avgp[t + 256] = 0.f;
  if (t < 128) avgp[t + 512] = 0.f;

  // stage 8 x-rows into LDS (coalesced float4)
  const float4* x4 = (const float4*)(x + (size_t)row0 * CDIM);
  float4* xs4 = (float4*)&xs[0][0];
#pragma unroll
  for (int i = 0; i < 4; ++i) xs4[t + i * 256] = x4[t + i * 256];
  __syncthreads();

  // ---- logits GEMM: each thread owns cols {t, t+256, (t+512 if t<128)} ----
  // f64 accumulation: argmax must match the reference bit-for-bit in practice.
  const int c0 = t, c1 = t + 256;
  const int c2 = (t < 128) ? (t + 512) : 639;  // clamp to stay in-bounds
  double a0[ROWS], a1[ROWS], a2[ROWS];
#pragma unroll
  for (int r = 0; r < ROWS; ++r) { a0[r] = 0.0; a1[r] = 0.0; a2[r] = 0.0; }

  const float* Wk = W;
  for (int k = 0; k < CDIM; ++k) {
    double w0 = (double)Wk[c0];
    double w1 = (double)Wk[c1];
    double w2 = (double)Wk[c2];
#pragma unroll
    for (int r = 0; r < ROWS; ++r) {
      double xv = (double)xs[r][k];
      a0[r] = fma(xv, w0, a0[r]);
      a1[r] = fma(xv, w1, a1[r]);
      a2[r] = fma(xv, w2, a2[r]);
    }
    Wk += MDIM;
  }
#pragma unroll
  for (int r = 0; r < ROWS; ++r) {
    lg[r][c0] = (float)(a0[r] + (double)b[c0]);
    lg[r][c1] = (float)(a1[r] + (double)b[c1]);
    if (t < 128) lg[r][c2] = (float)(a2[r] + (double)b[c2]);
  }
  __syncthreads();

  // ---- per-row argmax + softmax (wave per row, 4 waves / 8 rows) ----
  const int wave = t >> 6, lane = t & 63;
  for (int r = wave; r < ROWS; r += 4) {
    float m0 = -1e30f, m1 = -1e30f;
    int i0 = 0, i1 = VDIM;
    float e0v[5], e1v[5];
#pragma unroll
    for (int j = 0; j < 5; ++j) {
      int ca = lane + j * 64;          // 0..319
      float v = lg[r][ca];
      e0v[j] = v;
      if (v > m0) { m0 = v; i0 = ca; }
      float v2 = lg[r][VDIM + ca];     // 320..639
      e1v[j] = v2;
      if (v2 > m1) { m1 = v2; i1 = VDIM + ca; }
    }
    // wave-wide argmax, first-index tie-break (matches jnp.argmax)
#pragma unroll
    for (int off = 32; off > 0; off >>= 1) {
      float om = __shfl_xor(m0, off); int oi = __shfl_xor(i0, off);
      if (om > m0 || (om == m0 && oi < i0)) { m0 = om; i0 = oi; }
      om = __shfl_xor(m1, off); oi = __shfl_xor(i1, off);
      if (om > m1 || (om == m1 && oi < i1)) { m1 = om; i1 = oi; }
    }
    // softmax sums
    float z0 = 0.f, z1 = 0.f;
#pragma unroll
    for (int j = 0; j < 5; ++j) {
      e0v[j] = expf(e0v[j] - m0); z0 += e0v[j];
      e1v[j] = expf(e1v[j] - m1); z1 += e1v[j];
    }
#pragma unroll
    for (int off = 32; off > 0; off >>= 1) {
      z0 += __shfl_xor(z0, off);
      z1 += __shfl_xor(z1, off);
    }
    float r0 = 1.f / z0, r1 = 1.f / z1;
#pragma unroll
    for (int j = 0; j < 5; ++j) {
      atomicAdd(&avgp[lane + j * 64], e0v[j] * r0);
      atomicAdd(&avgp[VDIM + lane + j * 64], e1v[j] * r1);
    }
    if (lane == 0) {
      rowk[r][0] = i0;
      rowk[r][1] = i1 - VDIM;
      atomicAdd(&ws_hist[i0], 1.f);
      atomicAdd(&ws_hist[i1], 1.f);
    }
  }
  __syncthreads();

  // ---- codebook gather: out[n, g*128+d] = cb[(g*320 + k[n,g])*128 + d] ----
  const int g = t >> 7, dd = t & 127;
#pragma unroll
  for (int r = 0; r < ROWS; ++r) {
    int kk = rowk[r][g];
    out[(size_t)(row0 + r) * 256 + t] = cb[((size_t)(g * VDIM + kk)) * DDIM + dd];
  }

  // ---- flush block's avg_probs partial into replicated global accumulators ----
  float* dst = ws_avgp + (size_t)(blockIdx.x & (NREP - 1)) * MDIM;
  atomicAdd(&dst[t], avgp[t]);
  atomicAdd(&dst[t + 256], avgp[t + 256]);
  if (t < 128) atomicAdd(&dst[t + 512], avgp[t + 512]);
}

__global__ __launch_bounds__(256) void gvq_finalize_kernel(
    const float* __restrict__ ws_avgp, const float* __restrict__ ws_hist,
    float* __restrict__ out) {
  __shared__ double red[256];
  const int t = threadIdx.x;
  double pp[2] = {0.0, 0.0}, hp[2] = {0.0, 0.0};
  for (int c = t; c < MDIM; c += 256) {
    double s = 0.0;
    for (int rep = 0; rep < NREP; ++rep) s += (double)ws_avgp[rep * MDIM + c];
    double avg = s / (double)NROWS;
    double hard = (double)ws_hist[c] / (double)NROWS;
    int g = (c < VDIM) ? 0 : 1;
    pp[g] += avg * log(avg + 1e-7);
    hp[g] += hard * log(hard + 1e-7);
  }
  double vals[4] = {pp[0], pp[1], hp[0], hp[1]};
  double res[4];
  for (int i = 0; i < 4; ++i) {
    red[t] = vals[i];
    __syncthreads();
    for (int s = 128; s > 0; s >>= 1) {
      if (t < s) red[t] += red[t + s];
      __syncthreads();
    }
    res[i] = red[0];
    __syncthreads();
  }
  if (t == 0) {
    // code_perplexity then prob_perplexity, appended after the gather output
    out[OUTN]     = (float)(exp(-res[2]) + exp(-res[3]));
    out[OUTN + 1] = (float)(exp(-res[0]) + exp(-res[1]));
  }
}

extern "C" void kernel_launch(void* const* d_in, const int* in_sizes, int n_in,
                              void* d_out, int out_size, void* d_ws, size_t ws_size,
                              hipStream_t stream) {
  const float* x  = (const float*)d_in[0];   // (16,4096,512)
  const float* W  = (const float*)d_in[1];   // (512,640)
  const float* b  = (const float*)d_in[2];   // (640,)
  const float* cb = (const float*)d_in[3];   // (640,128)
  float* out = (float*)d_out;                // 16777216 + 2 floats
  float* ws = (float*)d_ws;
  float* ws_avgp = ws;                // NREP*MDIM floats
  float* ws_hist = ws + NREP * MDIM;  // MDIM floats

  const int zn = NREP * MDIM + MDIM;
  zero_ws_kernel<<<(zn + 255) / 256, 256, 0, stream>>>(ws, zn);
  gvq_main_kernel<<<NROWS / ROWS, 256, 0, stream>>>(x, W, b, cb, out, ws_avgp,
                                                    ws_hist);
  gvq_finalize_kernel<<<1, 256, 0, stream>>>(ws_avgp, ws_hist, out);
}

// Round 2
// 659.115 us; speedup vs baseline: 2.3732x; 2.3732x over previous
//
#include <hip/hip_runtime.h>
#include <math.h>

#define NROWS 65536      // B*T
#define CDIM 512         // C
#define MDIM 640         // G*V
#define VDIM 320         // NUM_VARS
#define DDIM 128
#define OUTN (NROWS * 256)
#define NREP 64
#define TAU 0.01f
#define QCAP 65536

typedef _Float16 half8 __attribute__((ext_vector_type(8)));
typedef float f32x4 __attribute__((ext_vector_type(4)));

// ---- ws layout (byte offsets) ----
#define WT_HI_OFF 0                       // 512*640 f16 = 655360 B
#define WT_LO_OFF 655360
#define KIDX_OFF  1310720                 // 65536*2 int = 524288 B
#define QUEUE_OFF 1835008                 // QCAP int = 262144 B
#define ZBASE     2097152                 // qcount int, then pad to 256
#define AVGP_OFF  (ZBASE + 256)           // NREP*640 f32
#define HIST_OFF  (AVGP_OFF + NREP * MDIM * 4)  // 640 f32
#define ZLEN_F    ((256 + NREP * MDIM * 4 + MDIM * 4) / 4)
#define WS_NEEDED (ZBASE + 256 + NREP * MDIM * 4 + MDIM * 4)

__global__ __launch_bounds__(256) void zero_ws_kernel(float* ws, int n) {
  int i = blockIdx.x * 256 + threadIdx.x;
  if (i < n) ws[i] = 0.f;
}

// ---- W -> transposed f16 hi/lo split: Wt[n][k] ----
__global__ __launch_bounds__(256) void prep_w_kernel(
    const float* __restrict__ W, _Float16* __restrict__ wh,
    _Float16* __restrict__ wl) {
  int idx = blockIdx.x * 256 + threadIdx.x;  // 512*640 = 327680
  int k = idx / MDIM, n = idx - k * MDIM;
  float w = W[idx];
  _Float16 h = (_Float16)w;
  wh[n * CDIM + k] = h;
  wl[n * CDIM + k] = (_Float16)(w - (float)h);
}

// ---- main fused GEMM(f16x3) + argmax/top2 + softmax avg_probs ----
// block: 64 rows x 640 cols; wave w: rows [32*(w&1),+32), group g=w>>1 (320 cols)
__global__ __launch_bounds__(256, 2) void gvq_gemm_kernel(
    const float* __restrict__ x, const float* __restrict__ bias,
    const _Float16* __restrict__ wt_hi, const _Float16* __restrict__ wt_lo,
    int* __restrict__ k_idx, int* __restrict__ queue, int* __restrict__ qcount,
    float* __restrict__ ws_avgp) {
  __shared__ alignas(16) _Float16 xs[2][2][64][40];  // [buf][hi/lo][row][k] 20.5 KB

  const int t = threadIdx.x;
  const int wave = t >> 6, lane = t & 63;
  const int quad = lane >> 4, l15 = lane & 15;
  const int row0 = blockIdx.x * 64;
  const int g = wave >> 1;
  const int rbase = (wave & 1) * 32;

  const int sr = t >> 2;          // staging row 0..63
  const int sk = (t & 3) * 8;     // staging k: 0,8,16,24

  f32x4 acc[2][20];
#pragma unroll
  for (int mt = 0; mt < 2; ++mt)
#pragma unroll
    for (int nt = 0; nt < 20; ++nt) acc[mt][nt] = (f32x4)0.f;

  const float4* xsrc = (const float4*)(x + (size_t)(row0 + sr) * CDIM + sk);
  float4 va = xsrc[0], vb = xsrc[1];

  const _Float16* whbase = wt_hi + (size_t)(g * VDIM + l15) * CDIM + quad * 8;
  const _Float16* wlbase = wt_lo + (size_t)(g * VDIM + l15) * CDIM + quad * 8;

#pragma unroll 1
  for (int ks = 0; ks < 16; ++ks) {
    // convert + stage into buf ks&1
    half8 hh, hl;
    float vv[8] = {va.x, va.y, va.z, va.w, vb.x, vb.y, vb.z, vb.w};
#pragma unroll
    for (int j = 0; j < 8; ++j) {
      hh[j] = (_Float16)vv[j];
      hl[j] = (_Float16)(vv[j] - (float)hh[j]);
    }
    *(half8*)&xs[ks & 1][0][sr][sk] = hh;
    *(half8*)&xs[ks & 1][1][sr][sk] = hl;
    if (ks < 15) { va = xsrc[(ks + 1) * 8]; vb = xsrc[(ks + 1) * 8 + 1]; }
    __syncthreads();

    half8 a_hi[2], a_lo[2];
#pragma unroll
    for (int mt = 0; mt < 2; ++mt) {
      a_hi[mt] = *(const half8*)&xs[ks & 1][0][rbase + mt * 16 + l15][quad * 8];
      a_lo[mt] = *(const half8*)&xs[ks & 1][1][rbase + mt * 16 + l15][quad * 8];
    }

    const _Float16* wh = whbase + ks * 32;
    const _Float16* wl = wlbase + ks * 32;
    half8 bh = *(const half8*)wh;
    half8 bl = *(const half8*)wl;
#pragma unroll
    for (int nt = 0; nt < 20; ++nt) {
      half8 bh2 = bh, bl2 = bl;
      if (nt < 19) {
        bh2 = *(const half8*)(wh + (size_t)(nt + 1) * 16 * CDIM);
        bl2 = *(const half8*)(wl + (size_t)(nt + 1) * 16 * CDIM);
      }
#pragma unroll
      for (int mt = 0; mt < 2; ++mt) {
        acc[mt][nt] = __builtin_amdgcn_mfma_f32_16x16x32_f16(a_hi[mt], bh, acc[mt][nt], 0, 0, 0);
        acc[mt][nt] = __builtin_amdgcn_mfma_f32_16x16x32_f16(a_hi[mt], bl, acc[mt][nt], 0, 0, 0);
        acc[mt][nt] = __builtin_amdgcn_mfma_f32_16x16x32_f16(a_lo[mt], bh, acc[mt][nt], 0, 0, 0);
      }
      bh = bh2; bl = bl2;
    }
    __syncthreads();
  }

  // add bias (zeros in this problem, but be faithful)
#pragma unroll
  for (int nt = 0; nt < 20; ++nt) {
    float bb = bias[g * VDIM + nt * 16 + l15];
#pragma unroll
    for (int mt = 0; mt < 2; ++mt) {
      acc[mt][nt][0] += bb; acc[mt][nt][1] += bb;
      acc[mt][nt][2] += bb; acc[mt][nt][3] += bb;
    }
  }

  // ---- epilogue: per (row) top2/argmax, softmax, avg_probs partials ----
  float pp[20];
#pragma unroll
  for (int nt = 0; nt < 20; ++nt) pp[nt] = 0.f;

#pragma unroll
  for (int mt = 0; mt < 2; ++mt) {
#pragma unroll
    for (int reg = 0; reg < 4; ++reg) {
      // this lane's row for (mt,reg): local = rbase + mt*16 + quad*4 + reg
      float m1 = -1e30f, m2 = -1e30f;
      int i1 = 0;
#pragma unroll
      for (int nt = 0; nt < 20; ++nt) {
        float v = acc[mt][nt][reg];
        int ci = nt * 16 + l15;
        if (v > m1) { m2 = m1; m1 = v; i1 = ci; }
        else if (v > m2) m2 = v;
      }
#pragma unroll
      for (int off = 1; off <= 8; off <<= 1) {
        float om1 = __shfl_xor(m1, off);
        int oi1 = __shfl_xor(i1, off);
        float om2 = __shfl_xor(m2, off);
        if (om1 > m1 || (om1 == m1 && oi1 < i1)) {
          m2 = fmaxf(m1, om2); m1 = om1; i1 = oi1;
        } else {
          m2 = fmaxf(m2, om1);
        }
      }
      // softmax denom
      float z = 0.f;
#pragma unroll
      for (int nt = 0; nt < 20; ++nt) z += __expf(acc[mt][nt][reg] - m1);
#pragma unroll
      for (int off = 1; off <= 8; off <<= 1) z += __shfl_xor(z, off);
      float rz = 1.f / z;
#pragma unroll
      for (int nt = 0; nt < 20; ++nt)
        pp[nt] += __expf(acc[mt][nt][reg] - m1) * rz;

      if (l15 == 0) {
        int grow = row0 + rbase + mt * 16 + quad * 4 + reg;
        k_idx[grow * 2 + g] = i1;
        if (m1 - m2 < TAU) {
          int qi = atomicAdd(qcount, 1);
          if (qi < QCAP) queue[qi] = grow * 2 + g;
        }
      }
    }
  }
  // reduce avg_probs partials across quads (lanes sharing the same col)
#pragma unroll
  for (int nt = 0; nt < 20; ++nt) {
    pp[nt] += __shfl_xor(pp[nt], 16);
    pp[nt] += __shfl_xor(pp[nt], 32);
  }
  if (quad == 0) {
    float* dst = ws_avgp + (size_t)(blockIdx.x & (NREP - 1)) * MDIM + g * VDIM + l15;
#pragma unroll
    for (int nt = 0; nt < 20; ++nt) atomicAdd(dst + nt * 16, pp[nt]);
  }
}

// ---- exact f64 recompute for near-tie rows ----
__global__ __launch_bounds__(256) void fixup_kernel(
    const float* __restrict__ x, const float* __restrict__ W,
    const float* __restrict__ bias, const int* __restrict__ queue,
    const int* __restrict__ qcount, int* __restrict__ k_idx) {
  __shared__ float xrow[CDIM];
  __shared__ double sval[256];
  __shared__ int sidx[256];
  const int t = threadIdx.x;
  int n = *qcount;
  if (n > QCAP) n = QCAP;
  for (int i = blockIdx.x; i < n; i += gridDim.x) {
    int e = queue[i];
    int row = e >> 1, g = e & 1;
    __syncthreads();
    xrow[t] = x[(size_t)row * CDIM + t];
    xrow[t + 256] = x[(size_t)row * CDIM + 256 + t];
    __syncthreads();
    double bv = -1e300;
    int bi = 0;
    for (int c = t; c < VDIM; c += 256) {
      const float* wp = W + g * VDIM + c;
      double a0 = 0, a1 = 0, a2 = 0, a3 = 0;
      for (int k = 0; k < CDIM; k += 4) {
        a0 = fma((double)xrow[k],     (double)wp[(size_t)k * MDIM], a0);
        a1 = fma((double)xrow[k + 1], (double)wp[(size_t)(k + 1) * MDIM], a1);
        a2 = fma((double)xrow[k + 2], (double)wp[(size_t)(k + 2) * MDIM], a2);
        a3 = fma((double)xrow[k + 3], (double)wp[(size_t)(k + 3) * MDIM], a3);
      }
      double a = ((a0 + a1) + (a2 + a3)) + (double)bias[g * VDIM + c];
      if (a > bv) { bv = a; bi = c; }  // c ascending -> first-index wins
    }
    sval[t] = bv; sidx[t] = bi;
    __syncthreads();
    for (int s = 128; s > 0; s >>= 1) {
      if (t < s) {
        if (sval[t + s] > sval[t] ||
            (sval[t + s] == sval[t] && sidx[t + s] < sidx[t])) {
          sval[t] = sval[t + s]; sidx[t] = sidx[t + s];
        }
      }
      __syncthreads();
    }
    if (t == 0) k_idx[row * 2 + g] = sidx[0];
  }
}

// ---- gather + histogram ----
__global__ __launch_bounds__(256) void gather_kernel(
    const int* __restrict__ k_idx, const float* __restrict__ cb,
    float* __restrict__ out, float* __restrict__ hist) {
  const int t = threadIdx.x;
  const int row0 = blockIdx.x * 16;
  const int g = t >> 7, d = t & 127;
#pragma unroll
  for (int r = 0; r < 16; ++r) {
    int row = row0 + r;
    int kk = k_idx[row * 2 + g];
    out[(size_t)row * 256 + t] = cb[((size_t)(g * VDIM + kk) << 7) + d];
    if (d == 0) atomicAdd(&hist[g * VDIM + kk], 1.f);
  }
}

__global__ __launch_bounds__(256) void gvq_finalize_kernel(
    const float* __restrict__ ws_avgp, const float* __restrict__ ws_hist,
    float* __restrict__ out) {
  __shared__ double red[256];
  const int t = threadIdx.x;
  double pp[2] = {0.0, 0.0}, hp[2] = {0.0, 0.0};
  for (int c = t; c < MDIM; c += 256) {
    double s = 0.0;
    for (int rep = 0; rep < NREP; ++rep) s += (double)ws_avgp[rep * MDIM + c];
    double avg = s / (double)NROWS;
    double hard = (double)ws_hist[c] / (double)NROWS;
    int g = (c < VDIM) ? 0 : 1;
    pp[g] += avg * log(avg + 1e-7);
    hp[g] += hard * log(hard + 1e-7);
  }
  double vals[4] = {pp[0], pp[1], hp[0], hp[1]};
  double res[4];
  for (int i = 0; i < 4; ++i) {
    red[t] = vals[i];
    __syncthreads();
    for (int s = 128; s > 0; s >>= 1) {
      if (t < s) red[t] += red[t + s];
      __syncthreads();
    }
    res[i] = red[0];
    __syncthreads();
  }
  if (t == 0) {
    out[OUTN]     = (float)(exp(-res[2]) + exp(-res[3]));
    out[OUTN + 1] = (float)(exp(-res[0]) + exp(-res[1]));
  }
}

// ================= fallback (round-1 verified f64 path) =================
__global__ __launch_bounds__(256) void fb_main_kernel(
    const float* __restrict__ x, const float* __restrict__ W,
    const float* __restrict__ b, const float* __restrict__ cb,
    float* __restrict__ out, float* __restrict__ ws_avgp,
    float* __restrict__ ws_hist) {
  __shared__ float xs[8][CDIM];
  __shared__ float lg[8][MDIM];
  __shared__ float avgp[MDIM];
  __shared__ int rowk[8][2];
  const int t = threadIdx.x;
  const int row0 = blockIdx.x * 8;
  avgp[t] = 0.f; avgp[t + 256] = 0.f;
  if (t < 128) avgp[t + 512] = 0.f;
  const float4* x4 = (const float4*)(x + (size_t)row0 * CDIM);
  float4* xs4 = (float4*)&xs[0][0];
#pragma unroll
  for (int i = 0; i < 4; ++i) xs4[t + i * 256] = x4[t + i * 256];
  __syncthreads();
  const int c0 = t, c1 = t + 256;
  const int c2 = (t < 128) ? (t + 512) : 639;
  double a0[8], a1[8], a2[8];
#pragma unroll
  for (int r = 0; r < 8; ++r) { a0[r] = 0.0; a1[r] = 0.0; a2[r] = 0.0; }
  const float* Wk = W;
  for (int k = 0; k < CDIM; ++k) {
    double w0 = (double)Wk[c0], w1 = (double)Wk[c1], w2 = (double)Wk[c2];
#pragma unroll
    for (int r = 0; r < 8; ++r) {
      double xv = (double)xs[r][k];
      a0[r] = fma(xv, w0, a0[r]);
      a1[r] = fma(xv, w1, a1[r]);
      a2[r] = fma(xv, w2, a2[r]);
    }
    Wk += MDIM;
  }
#pragma unroll
  for (int r = 0; r < 8; ++r) {
    lg[r][c0] = (float)(a0[r] + (double)b[c0]);
    lg[r][c1] = (float)(a1[r] + (double)b[c1]);
    if (t < 128) lg[r][c2] = (float)(a2[r] + (double)b[c2]);
  }
  __syncthreads();
  const int wave = t >> 6, lane = t & 63;
  for (int r = wave; r < 8; r += 4) {
    float m0 = -1e30f, m1 = -1e30f;
    int i0 = 0, i1 = VDIM;
    float e0v[5], e1v[5];
#pragma unroll
    for (int j = 0; j < 5; ++j) {
      int ca = lane + j * 64;
      float v = lg[r][ca]; e0v[j] = v;
      if (v > m0) { m0 = v; i0 = ca; }
      float v2 = lg[r][VDIM + ca]; e1v[j] = v2;
      if (v2 > m1) { m1 = v2; i1 = VDIM + ca; }
    }
#pragma unroll
    for (int off = 32; off > 0; off >>= 1) {
      float om = __shfl_xor(m0, off); int oi = __shfl_xor(i0, off);
      if (om > m0 || (om == m0 && oi < i0)) { m0 = om; i0 = oi; }
      om = __shfl_xor(m1, off); oi = __shfl_xor(i1, off);
      if (om > m1 || (om == m1 && oi < i1)) { m1 = om; i1 = oi; }
    }
    float z0 = 0.f, z1 = 0.f;
#pragma unroll
    for (int j = 0; j < 5; ++j) {
      e0v[j] = expf(e0v[j] - m0); z0 += e0v[j];
      e1v[j] = expf(e1v[j] - m1); z1 += e1v[j];
    }
#pragma unroll
    for (int off = 32; off > 0; off >>= 1) {
      z0 += __shfl_xor(z0, off); z1 += __shfl_xor(z1, off);
    }
    float r0 = 1.f / z0, r1 = 1.f / z1;
#pragma unroll
    for (int j = 0; j < 5; ++j) {
      atomicAdd(&avgp[lane + j * 64], e0v[j] * r0);
      atomicAdd(&avgp[VDIM + lane + j * 64], e1v[j] * r1);
    }
    if (lane == 0) {
      rowk[r][0] = i0; rowk[r][1] = i1 - VDIM;
      atomicAdd(&ws_hist[i0], 1.f);
      atomicAdd(&ws_hist[i1], 1.f);
    }
  }
  __syncthreads();
  const int g = t >> 7, dd = t & 127;
#pragma unroll
  for (int r = 0; r < 8; ++r) {
    int kk = rowk[r][g];
    out[(size_t)(row0 + r) * 256 + t] = cb[((size_t)(g * VDIM + kk)) * DDIM + dd];
  }
  float* dst = ws_avgp + (size_t)(blockIdx.x & (NREP - 1)) * MDIM;
  atomicAdd(&dst[t], avgp[t]);
  atomicAdd(&dst[t + 256], avgp[t + 256]);
  if (t < 128) atomicAdd(&dst[t + 512], avgp[t + 512]);
}

extern "C" void kernel_launch(void* const* d_in, const int* in_sizes, int n_in,
                              void* d_out, int out_size, void* d_ws, size_t ws_size,
                              hipStream_t stream) {
  const float* x  = (const float*)d_in[0];
  const float* W  = (const float*)d_in[1];
  const float* b  = (const float*)d_in[2];
  const float* cb = (const float*)d_in[3];
  float* out = (float*)d_out;
  char* ws = (char*)d_ws;

  if (ws_size >= (size_t)WS_NEEDED) {
    _Float16* wt_hi = (_Float16*)(ws + WT_HI_OFF);
    _Float16* wt_lo = (_Float16*)(ws + WT_LO_OFF);
    int* k_idx = (int*)(ws + KIDX_OFF);
    int* queue = (int*)(ws + QUEUE_OFF);
    int* qcount = (int*)(ws + ZBASE);
    float* avgp = (float*)(ws + AVGP_OFF);
    float* hist = (float*)(ws + HIST_OFF);

    prep_w_kernel<<<(CDIM * MDIM) / 256, 256, 0, stream>>>(W, wt_hi, wt_lo);
    zero_ws_kernel<<<(ZLEN_F + 255) / 256, 256, 0, stream>>>((float*)(ws + ZBASE), ZLEN_F);
    gvq_gemm_kernel<<<NROWS / 64, 256, 0, stream>>>(x, b, wt_hi, wt_lo, k_idx,
                                                    queue, qcount, avgp);
    fixup_kernel<<<512, 256, 0, stream>>>(x, W, b, queue, qcount, k_idx);
    gather_kernel<<<NROWS / 16, 256, 0, stream>>>(k_idx, cb, out, hist);
    gvq_finalize_kernel<<<1, 256, 0, stream>>>(avgp, hist, out);
  } else {
    float* ws_avgp = (float*)ws;
    float* ws_hist = (float*)ws + NREP * MDIM;
    const int zn = NREP * MDIM + MDIM;
    zero_ws_kernel<<<(zn + 255) / 256, 256, 0, stream>>>((float*)ws, zn);
    fb_main_kernel<<<NROWS / 8, 256, 0, stream>>>(x, W, b, cb, out, ws_avgp, ws_hist);
    gvq_finalize_kernel<<<1, 256, 0, stream>>>(ws_avgp, ws_hist, out);
  }
}

// Round 3
// 640.195 us; speedup vs baseline: 2.4434x; 1.0296x over previous
//
#include <hip/hip_runtime.h>
#include <math.h>

#define NROWS 65536
#define CDIM 512
#define MDIM 640
#define VDIM 320
#define DDIM 128
#define OUTN (NROWS * 256)
#define NREP 32
#define TAU1 0.30f
#define TAU2 0.01f
#define Q1CAP 32768
#define Q2CAP 8192

typedef _Float16 half8 __attribute__((ext_vector_type(8)));
typedef float f32x4 __attribute__((ext_vector_type(4)));

// ---- ws layout (byte offsets) ----
#define WPK_HI_OFF 0                         // 327680 f16 = 655360 B
#define WPK_LO_OFF 655360
#define KIDX_OFF   1310720                   // 65536*2 int
#define Q1G0_OFF   1835008                   // Q1CAP int
#define Q1G1_OFF   1966080
#define Q2_OFF     2097152                   // Q2CAP int
#define CNT_OFF    2129920                   // qc0, qc1, qc2 (+pad 256)
#define AVGP_OFF   2130176                   // NREP*640 f32
#define HIST_OFF   (AVGP_OFF + NREP * MDIM * 4)
#define WS_NEEDED  (HIST_OFF + MDIM * 4)     // 2214656 <= R2's proven 2263808
#define ZLEN_F     ((WS_NEEDED - CNT_OFF) / 4)

__global__ __launch_bounds__(256) void zero_ws_kernel(float* ws, int n) {
  int i = blockIdx.x * 256 + threadIdx.x;
  if (i < n) ws[i] = 0.f;
}

// ---- W -> packed MFMA B-fragment order, hi/lo f16 split ----
// frag f = (ks*2+g)*20+nt ; element [f*512 + lane*8 + j]
// lane: l15 = col-in-tile, quad = k-subchunk; j = k offset
__global__ __launch_bounds__(256) void prep_wpk_kernel(
    const float* __restrict__ W, _Float16* __restrict__ ph,
    _Float16* __restrict__ pl) {
  int idx = blockIdx.x * 256 + threadIdx.x;  // 40960 lane-slots
  if (idx >= 40960) return;
  int lane = idx & 63;
  int rest = idx >> 6;        // (ks*2+g)*20+nt
  int nt = rest % 20;
  int gks = rest / 20;
  int g = gks & 1, ks = gks >> 1;
  int col = g * VDIM + nt * 16 + (lane & 15);
  int kbase = ks * 32 + (lane >> 4) * 8;
  _Float16 hh[8], ll[8];
#pragma unroll
  for (int j = 0; j < 8; ++j) {
    float w = W[(size_t)(kbase + j) * MDIM + col];
    _Float16 h = (_Float16)w;
    hh[j] = h;
    ll[j] = (_Float16)(w - (float)h);
  }
  *(half8*)&ph[(size_t)idx * 8] = *(half8*)hh;
  *(half8*)&pl[(size_t)idx * 8] = *(half8*)ll;
}

// ---- tier-1: f16-hi GEMM + argmax/top2 + softmax avg_probs ----
// 512 threads = 8 waves; wave w: g = w&1, rows rbase=(w>>1)*32 (2 mt of 16)
__global__ __launch_bounds__(512, 2) void t1_gemm_kernel(
    const float* __restrict__ x, const float* __restrict__ bias,
    const _Float16* __restrict__ wpk_hi, int* __restrict__ k_idx,
    int* __restrict__ q1g0, int* __restrict__ q1g1, int* __restrict__ qc,
    float* __restrict__ ws_avgp) {
  __shared__ alignas(16) _Float16 xs[2][128][40];  // 20.5 KB

  const int t = threadIdx.x;
  const int wave = t >> 6, lane = t & 63;
  const int quad = lane >> 4, l15 = lane & 15;
  const int row0 = blockIdx.x * 128;
  const int g = wave & 1;
  const int rbase = (wave >> 1) * 32;

  const int sr = t >> 2;           // staging row 0..127
  const int sk = (t & 3) * 8;      // k offset 0,8,16,24

  f32x4 acc[2][20];
#pragma unroll
  for (int mt = 0; mt < 2; ++mt)
#pragma unroll
    for (int nt = 0; nt < 20; ++nt) acc[mt][nt] = (f32x4)0.f;

  const float4* xsrc4 = (const float4*)x + (size_t)(row0 + sr) * 128 + (sk >> 2);
  float4 va = xsrc4[0], vb = xsrc4[1];

#pragma unroll 1
  for (int ks = 0; ks < 16; ++ks) {
    half8 hh;
    float vv[8] = {va.x, va.y, va.z, va.w, vb.x, vb.y, vb.z, vb.w};
#pragma unroll
    for (int j = 0; j < 8; ++j) hh[j] = (_Float16)vv[j];
    *(half8*)&xs[ks & 1][sr][sk] = hh;
    if (ks < 15) { va = xsrc4[(ks + 1) * 8]; vb = xsrc4[(ks + 1) * 8 + 1]; }

    // issue B prefetch before the barrier (independent of LDS)
    const _Float16* bptr = wpk_hi + ((size_t)(ks * 2 + g) * 20) * 512 + lane * 8;
    half8 b0 = *(const half8*)(bptr);
    half8 b1 = *(const half8*)(bptr + 512);
    half8 b2 = *(const half8*)(bptr + 1024);
    __syncthreads();

    half8 a0 = *(const half8*)&xs[ks & 1][rbase + l15][quad * 8];
    half8 a1 = *(const half8*)&xs[ks & 1][rbase + 16 + l15][quad * 8];

#pragma unroll
    for (int nt = 0; nt < 20; ++nt) {
      half8 bn = b0;
      if (nt < 17) bn = *(const half8*)(bptr + (size_t)(nt + 3) * 512);
      acc[0][nt] = __builtin_amdgcn_mfma_f32_16x16x32_f16(a0, b0, acc[0][nt], 0, 0, 0);
      acc[1][nt] = __builtin_amdgcn_mfma_f32_16x16x32_f16(a1, b0, acc[1][nt], 0, 0, 0);
      b0 = b1; b1 = b2; b2 = bn;
    }
  }

  // bias
#pragma unroll
  for (int nt = 0; nt < 20; ++nt) {
    float bb = bias[g * VDIM + nt * 16 + l15];
#pragma unroll
    for (int mt = 0; mt < 2; ++mt) {
      acc[mt][nt][0] += bb; acc[mt][nt][1] += bb;
      acc[mt][nt][2] += bb; acc[mt][nt][3] += bb;
    }
  }

  // ---- epilogue: top2/argmax + softmax partials ----
  int* qg = (g == 0) ? q1g0 : q1g1;
  float pp[20];
#pragma unroll
  for (int nt = 0; nt < 20; ++nt) pp[nt] = 0.f;

#pragma unroll
  for (int mt = 0; mt < 2; ++mt) {
#pragma unroll
    for (int reg = 0; reg < 4; ++reg) {
      float m1 = -1e30f, m2 = -1e30f;
      int i1 = 0;
#pragma unroll
      for (int nt = 0; nt < 20; ++nt) {
        float v = acc[mt][nt][reg];
        int ci = nt * 16 + l15;
        if (v > m1) { m2 = m1; m1 = v; i1 = ci; }
        else if (v > m2) m2 = v;
      }
#pragma unroll
      for (int off = 1; off <= 8; off <<= 1) {
        float om1 = __shfl_xor(m1, off);
        int oi1 = __shfl_xor(i1, off);
        float om2 = __shfl_xor(m2, off);
        if (om1 > m1 || (om1 == m1 && oi1 < i1)) {
          m2 = fmaxf(m1, om2); m1 = om1; i1 = oi1;
        } else {
          m2 = fmaxf(m2, om1);
        }
      }
      float z = 0.f;
#pragma unroll
      for (int nt = 0; nt < 20; ++nt) z += __expf(acc[mt][nt][reg] - m1);
#pragma unroll
      for (int off = 1; off <= 8; off <<= 1) z += __shfl_xor(z, off);
      float rz = 1.f / z;
#pragma unroll
      for (int nt = 0; nt < 20; ++nt)
        pp[nt] += __expf(acc[mt][nt][reg] - m1) * rz;

      if (l15 == 0) {
        int grow = row0 + rbase + mt * 16 + quad * 4 + reg;
        k_idx[grow * 2 + g] = i1;
        if (m1 - m2 < TAU1) {
          int qi = atomicAdd(&qc[g], 1);
          if (qi < Q1CAP) qg[qi] = grow;
        }
      }
    }
  }
#pragma unroll
  for (int nt = 0; nt < 20; ++nt) {
    pp[nt] += __shfl_xor(pp[nt], 16);
    pp[nt] += __shfl_xor(pp[nt], 32);
  }
  if (quad == 0) {
    float* dst = ws_avgp + (size_t)(blockIdx.x & (NREP - 1)) * MDIM + g * VDIM + l15;
#pragma unroll
    for (int nt = 0; nt < 20; ++nt) atomicAdd(dst + nt * 16, pp[nt]);
  }
}

// ---- tier-2: f16x3 exact-ish recompute of flagged (row,g) entries ----
// 256 threads = 4 waves; wave w handles 16 entries (one 16-row MFMA tile)
__global__ __launch_bounds__(256) void t2_kernel(
    const float* __restrict__ x, const float* __restrict__ bias,
    const _Float16* __restrict__ wpk_hi, const _Float16* __restrict__ wpk_lo,
    const int* __restrict__ queue, const int* __restrict__ qc, int g,
    int* __restrict__ k_idx, int* __restrict__ q2, int* __restrict__ qc2) {
  const int t = threadIdx.x;
  const int wave = t >> 6, lane = t & 63;
  const int quad = lane >> 4, l15 = lane & 15;
  int n = qc[g];
  if (n > Q1CAP) n = Q1CAP;

  for (int tbase0 = blockIdx.x * 64; tbase0 < n; tbase0 += gridDim.x * 64) {
    int tbase = tbase0 + wave * 16;
    int e = tbase + l15;
    int row = (e < n) ? queue[e] : 0;

    f32x4 acc[20];
#pragma unroll
    for (int nt = 0; nt < 20; ++nt) acc[nt] = (f32x4)0.f;

    const float4* xp = (const float4*)x + (size_t)row * 128 + (quad * 8 >> 2);
#pragma unroll 1
    for (int ks = 0; ks < 16; ++ks) {
      float4 va = xp[ks * 8], vb = xp[ks * 8 + 1];
      half8 ah, al;
      float vv[8] = {va.x, va.y, va.z, va.w, vb.x, vb.y, vb.z, vb.w};
#pragma unroll
      for (int j = 0; j < 8; ++j) {
        ah[j] = (_Float16)vv[j];
        al[j] = (_Float16)(vv[j] - (float)ah[j]);
      }
      const _Float16* bp = wpk_hi + ((size_t)(ks * 2 + g) * 20) * 512 + lane * 8;
      const _Float16* bpl = wpk_lo + ((size_t)(ks * 2 + g) * 20) * 512 + lane * 8;
#pragma unroll
      for (int nt = 0; nt < 20; ++nt) {
        half8 bh = *(const half8*)(bp + (size_t)nt * 512);
        half8 bl = *(const half8*)(bpl + (size_t)nt * 512);
        acc[nt] = __builtin_amdgcn_mfma_f32_16x16x32_f16(ah, bh, acc[nt], 0, 0, 0);
        acc[nt] = __builtin_amdgcn_mfma_f32_16x16x32_f16(ah, bl, acc[nt], 0, 0, 0);
        acc[nt] = __builtin_amdgcn_mfma_f32_16x16x32_f16(al, bh, acc[nt], 0, 0, 0);
      }
    }
#pragma unroll
    for (int reg = 0; reg < 4; ++reg) {
      float m1 = -1e30f, m2 = -1e30f;
      int i1 = 0;
#pragma unroll
      for (int nt = 0; nt < 20; ++nt) {
        float v = acc[nt][reg] + bias[g * VDIM + nt * 16 + l15];
        int ci = nt * 16 + l15;
        if (v > m1) { m2 = m1; m1 = v; i1 = ci; }
        else if (v > m2) m2 = v;
      }
#pragma unroll
      for (int off = 1; off <= 8; off <<= 1) {
        float om1 = __shfl_xor(m1, off);
        int oi1 = __shfl_xor(i1, off);
        float om2 = __shfl_xor(m2, off);
        if (om1 > m1 || (om1 == m1 && oi1 < i1)) {
          m2 = fmaxf(m1, om2); m1 = om1; i1 = oi1;
        } else {
          m2 = fmaxf(m2, om1);
        }
      }
      if (l15 == 0) {
        int ew = tbase + quad * 4 + reg;
        if (ew < n) {
          int rw = queue[ew];
          k_idx[rw * 2 + g] = i1;
          if (m1 - m2 < TAU2) {
            int qi = atomicAdd(qc2, 1);
            if (qi < Q2CAP) q2[qi] = rw * 2 + g;
          }
        }
      }
    }
  }
}

// ---- tier-3: exact f64 recompute (verified in R1/R2) ----
__global__ __launch_bounds__(256) void fixup_kernel(
    const float* __restrict__ x, const float* __restrict__ W,
    const float* __restrict__ bias, const int* __restrict__ queue,
    const int* __restrict__ qcount, int* __restrict__ k_idx) {
  __shared__ float xrow[CDIM];
  __shared__ double sval[256];
  __shared__ int sidx[256];
  const int t = threadIdx.x;
  int n = *qcount;
  if (n > Q2CAP) n = Q2CAP;
  for (int i = blockIdx.x; i < n; i += gridDim.x) {
    int e = queue[i];
    int row = e >> 1, g = e & 1;
    __syncthreads();
    xrow[t] = x[(size_t)row * CDIM + t];
    xrow[t + 256] = x[(size_t)row * CDIM + 256 + t];
    __syncthreads();
    double bv = -1e300;
    int bi = 0;
    for (int c = t; c < VDIM; c += 256) {
      const float* wp = W + g * VDIM + c;
      double a0 = 0, a1 = 0, a2 = 0, a3 = 0;
      for (int k = 0; k < CDIM; k += 4) {
        a0 = fma((double)xrow[k],     (double)wp[(size_t)k * MDIM], a0);
        a1 = fma((double)xrow[k + 1], (double)wp[(size_t)(k + 1) * MDIM], a1);
        a2 = fma((double)xrow[k + 2], (double)wp[(size_t)(k + 2) * MDIM], a2);
        a3 = fma((double)xrow[k + 3], (double)wp[(size_t)(k + 3) * MDIM], a3);
      }
      double a = ((a0 + a1) + (a2 + a3)) + (double)bias[g * VDIM + c];
      if (a > bv) { bv = a; bi = c; }
    }
    sval[t] = bv; sidx[t] = bi;
    __syncthreads();
    for (int s = 128; s > 0; s >>= 1) {
      if (t < s) {
        if (sval[t + s] > sval[t] ||
            (sval[t + s] == sval[t] && sidx[t + s] < sidx[t])) {
          sval[t] = sval[t + s]; sidx[t] = sidx[t + s];
        }
      }
      __syncthreads();
    }
    if (t == 0) k_idx[row * 2 + g] = sidx[0];
  }
}

// ---- gather (float4) + histogram ----
__global__ __launch_bounds__(256) void gather_kernel(
    const int* __restrict__ k_idx, const float* __restrict__ cb,
    float* __restrict__ out, float* __restrict__ hist) {
  const int t = threadIdx.x;
  const int row0 = blockIdx.x * 16;
  const int r4 = t >> 6, f4 = t & 63;
  const int g = f4 >> 5, d4 = f4 & 31;
  const float4* cb4 = (const float4*)cb;
  float4* out4 = (float4*)out;
#pragma unroll
  for (int rr = 0; rr < 4; ++rr) {
    int row = row0 + rr * 4 + r4;
    int kk = k_idx[row * 2 + g];
    out4[(size_t)row * 64 + f4] = cb4[(size_t)(g * VDIM + kk) * 32 + d4];
    if (d4 == 0) atomicAdd(&hist[g * VDIM + kk], 1.f);
  }
}

__global__ __launch_bounds__(256) void gvq_finalize_kernel(
    const float* __restrict__ ws_avgp, const float* __restrict__ ws_hist,
    float* __restrict__ out) {
  __shared__ double red[256];
  const int t = threadIdx.x;
  double pp[2] = {0.0, 0.0}, hp[2] = {0.0, 0.0};
  for (int c = t; c < MDIM; c += 256) {
    double s = 0.0;
    for (int rep = 0; rep < NREP; ++rep) s += (double)ws_avgp[rep * MDIM + c];
    double avg = s / (double)NROWS;
    double hard = (double)ws_hist[c] / (double)NROWS;
    int g = (c < VDIM) ? 0 : 1;
    pp[g] += avg * log(avg + 1e-7);
    hp[g] += hard * log(hard + 1e-7);
  }
  double vals[4] = {pp[0], pp[1], hp[0], hp[1]};
  double res[4];
  for (int i = 0; i < 4; ++i) {
    red[t] = vals[i];
    __syncthreads();
    for (int s = 128; s > 0; s >>= 1) {
      if (t < s) red[t] += red[t + s];
      __syncthreads();
    }
    res[i] = red[0];
    __syncthreads();
  }
  if (t == 0) {
    out[OUTN]     = (float)(exp(-res[2]) + exp(-res[3]));
    out[OUTN + 1] = (float)(exp(-res[0]) + exp(-res[1]));
  }
}

// ================= fallback (round-1 verified f64 path) =================
__global__ __launch_bounds__(256) void fb_main_kernel(
    const float* __restrict__ x, const float* __restrict__ W,
    const float* __restrict__ b, const float* __restrict__ cb,
    float* __restrict__ out, float* __restrict__ ws_avgp,
    float* __restrict__ ws_hist) {
  __shared__ float xs[8][CDIM];
  __shared__ float lg[8][MDIM];
  __shared__ float avgp[MDIM];
  __shared__ int rowk[8][2];
  const int t = threadIdx.x;
  const int row0 = blockIdx.x * 8;
  avgp[t] = 0.f; avgp[t + 256] = 0.f;
  if (t < 128) avgp[t + 512] = 0.f;
  const float4* x4 = (const float4*)(x + (size_t)row0 * CDIM);
  float4* xs4 = (float4*)&xs[0][0];
#pragma unroll
  for (int i = 0; i < 4; ++i) xs4[t + i * 256] = x4[t + i * 256];
  __syncthreads();
  const int c0 = t, c1 = t + 256;
  const int c2 = (t < 128) ? (t + 512) : 639;
  double a0[8], a1[8], a2[8];
#pragma unroll
  for (int r = 0; r < 8; ++r) { a0[r] = 0.0; a1[r] = 0.0; a2[r] = 0.0; }
  const float* Wk = W;
  for (int k = 0; k < CDIM; ++k) {
    double w0 = (double)Wk[c0], w1 = (double)Wk[c1], w2 = (double)Wk[c2];
#pragma unroll
    for (int r = 0; r < 8; ++r) {
      double xv = (double)xs[r][k];
      a0[r] = fma(xv, w0, a0[r]);
      a1[r] = fma(xv, w1, a1[r]);
      a2[r] = fma(xv, w2, a2[r]);
    }
    Wk += MDIM;
  }
#pragma unroll
  for (int r = 0; r < 8; ++r) {
    lg[r][c0] = (float)(a0[r] + (double)b[c0]);
    lg[r][c1] = (float)(a1[r] + (double)b[c1]);
    if (t < 128) lg[r][c2] = (float)(a2[r] + (double)b[c2]);
  }
  __syncthreads();
  const int wave = t >> 6, lane = t & 63;
  for (int r = wave; r < 8; r += 4) {
    float m0 = -1e30f, m1 = -1e30f;
    int i0 = 0, i1 = VDIM;
    float e0v[5], e1v[5];
#pragma unroll
    for (int j = 0; j < 5; ++j) {
      int ca = lane + j * 64;
      float v = lg[r][ca]; e0v[j] = v;
      if (v > m0) { m0 = v; i0 = ca; }
      float v2 = lg[r][VDIM + ca]; e1v[j] = v2;
      if (v2 > m1) { m1 = v2; i1 = VDIM + ca; }
    }
#pragma unroll
    for (int off = 32; off > 0; off >>= 1) {
      float om = __shfl_xor(m0, off); int oi = __shfl_xor(i0, off);
      if (om > m0 || (om == m0 && oi < i0)) { m0 = om; i0 = oi; }
      om = __shfl_xor(m1, off); oi = __shfl_xor(i1, off);
      if (om > m1 || (om == m1 && oi < i1)) { m1 = om; i1 = oi; }
    }
    float z0 = 0.f, z1 = 0.f;
#pragma unroll
    for (int j = 0; j < 5; ++j) {
      e0v[j] = expf(e0v[j] - m0); z0 += e0v[j];
      e1v[j] = expf(e1v[j] - m1); z1 += e1v[j];
    }
#pragma unroll
    for (int off = 32; off > 0; off >>= 1) {
      z0 += __shfl_xor(z0, off); z1 += __shfl_xor(z1, off);
    }
    float r0 = 1.f / z0, r1 = 1.f / z1;
#pragma unroll
    for (int j = 0; j < 5; ++j) {
      atomicAdd(&avgp[lane + j * 64], e0v[j] * r0);
      atomicAdd(&avgp[VDIM + lane + j * 64], e1v[j] * r1);
    }
    if (lane == 0) {
      rowk[r][0] = i0; rowk[r][1] = i1 - VDIM;
      atomicAdd(&ws_hist[i0], 1.f);
      atomicAdd(&ws_hist[i1], 1.f);
    }
  }
  __syncthreads();
  const int g = t >> 7, dd = t & 127;
#pragma unroll
  for (int r = 0; r < 8; ++r) {
    int kk = rowk[r][g];
    out[(size_t)(row0 + r) * 256 + t] = cb[((size_t)(g * VDIM + kk)) * DDIM + dd];
  }
  float* dst = ws_avgp + (size_t)(blockIdx.x & 31) * MDIM;
  atomicAdd(&dst[t], avgp[t]);
  atomicAdd(&dst[t + 256], avgp[t + 256]);
  if (t < 128) atomicAdd(&dst[t + 512], avgp[t + 512]);
}

extern "C" void kernel_launch(void* const* d_in, const int* in_sizes, int n_in,
                              void* d_out, int out_size, void* d_ws, size_t ws_size,
                              hipStream_t stream) {
  const float* x  = (const float*)d_in[0];
  const float* W  = (const float*)d_in[1];
  const float* b  = (const float*)d_in[2];
  const float* cb = (const float*)d_in[3];
  float* out = (float*)d_out;
  char* ws = (char*)d_ws;

  if (ws_size >= (size_t)WS_NEEDED) {
    _Float16* wpk_hi = (_Float16*)(ws + WPK_HI_OFF);
    _Float16* wpk_lo = (_Float16*)(ws + WPK_LO_OFF);
    int* k_idx = (int*)(ws + KIDX_OFF);
    int* q1g0 = (int*)(ws + Q1G0_OFF);
    int* q1g1 = (int*)(ws + Q1G1_OFF);
    int* q2   = (int*)(ws + Q2_OFF);
    int* qc   = (int*)(ws + CNT_OFF);      // qc[0], qc[1] tier-1; qc[2] tier-2
    float* avgp = (float*)(ws + AVGP_OFF);
    float* hist = (float*)(ws + HIST_OFF);

    prep_wpk_kernel<<<160, 256, 0, stream>>>(W, wpk_hi, wpk_lo);
    zero_ws_kernel<<<(ZLEN_F + 255) / 256, 256, 0, stream>>>((float*)(ws + CNT_OFF), ZLEN_F);
    t1_gemm_kernel<<<NROWS / 128, 512, 0, stream>>>(x, b, wpk_hi, k_idx, q1g0,
                                                    q1g1, qc, avgp);
    t2_kernel<<<128, 256, 0, stream>>>(x, b, wpk_hi, wpk_lo, q1g0, qc, 0, k_idx,
                                       q2, qc + 2);
    t2_kernel<<<128, 256, 0, stream>>>(x, b, wpk_hi, wpk_lo, q1g1, qc, 1, k_idx,
                                       q2, qc + 2);
    fixup_kernel<<<256, 256, 0, stream>>>(x, W, b, q2, qc + 2, k_idx);
    gather_kernel<<<NROWS / 16, 256, 0, stream>>>(k_idx, cb, out, hist);
    gvq_finalize_kernel<<<1, 256, 0, stream>>>(avgp, hist, out);
  } else {
    float* ws_avgp = (float*)ws;
    float* ws_hist = (float*)ws + NREP * MDIM;
    const int zn = NREP * MDIM + MDIM;
    zero_ws_kernel<<<(zn + 255) / 256, 256, 0, stream>>>((float*)ws, zn);
    fb_main_kernel<<<NROWS / 8, 256, 0, stream>>>(x, W, b, cb, out, ws_avgp, ws_hist);
    gvq_finalize_kernel<<<1, 256, 0, stream>>>(ws_avgp, ws_hist, out);
  }
}

// Round 4
// 633.225 us; speedup vs baseline: 2.4702x; 1.0110x over previous
//
#include <hip/hip_runtime.h>
#include <math.h>

#define NROWS 65536
#define CDIM 512
#define MDIM 640
#define VDIM 320
#define DDIM 128
#define OUTN (NROWS * 256)
#define NREP 32
#define TAU1 0.30f
#define TAU2 0.01f
#define Q1CAP 32768
#define Q2CAP 8192

typedef _Float16 half8 __attribute__((ext_vector_type(8)));
typedef float f32x4 __attribute__((ext_vector_type(4)));

// ---- ws layout (byte offsets) ----
#define WPK_HI_OFF 0                         // 327680 f16 = 655360 B
#define WPK_LO_OFF 655360
#define KIDX_OFF   1310720                   // 65536*2 int
#define Q1G0_OFF   1835008                   // Q1CAP int
#define Q1G1_OFF   1966080
#define Q2_OFF     2097152                   // Q2CAP int
#define CNT_OFF    2129920                   // qc0,qc1,qc2 (+pad 256)
#define AVGP_OFF   2130176                   // NREP*640 f32
#define HIST_OFF   (AVGP_OFF + NREP * MDIM * 4)
#define WS_NEEDED  (HIST_OFF + MDIM * 4)     // 2214656 (same as proven R3)
#define ZLEN_F     ((WS_NEEDED - CNT_OFF) / 4)   // 21184 floats
#define ZBLOCKS    ((ZLEN_F + 255) / 256)        // 83

// ---- prep: pack W into MFMA B-fragment order (hi/lo) + zero counters ----
__global__ __launch_bounds__(256) void prep_kernel(
    const float* __restrict__ W, _Float16* __restrict__ ph,
    _Float16* __restrict__ pl, float* __restrict__ zbase) {
  int bid = blockIdx.x;
  int t = threadIdx.x;
  if (bid < 160) {
    int idx = bid * 256 + t;  // 40960 lane-slots
    int lane = idx & 63;
    int rest = idx >> 6;      // (ks*2+g)*20+nt  == ks*40 + g*20 + nt
    int nt = rest % 20;
    int gks = rest / 20;
    int g = gks & 1, ks = gks >> 1;
    int col = g * VDIM + nt * 16 + (lane & 15);
    int kbase = ks * 32 + (lane >> 4) * 8;
    _Float16 hh[8], ll[8];
#pragma unroll
    for (int j = 0; j < 8; ++j) {
      float w = W[(size_t)(kbase + j) * MDIM + col];
      _Float16 h = (_Float16)w;
      hh[j] = h;
      ll[j] = (_Float16)(w - (float)h);
    }
    *(half8*)&ph[(size_t)idx * 8] = *(half8*)hh;
    *(half8*)&pl[(size_t)idx * 8] = *(half8*)ll;
  } else {
    int i = (bid - 160) * 256 + t;
    if (i < ZLEN_F) zbase[i] = 0.f;
  }
}

// ---- tier-1: f16-hi GEMM (W staged in LDS) + argmax/top2 + softmax +
//      fused gather-write + histogram ----
// 512 threads = 8 waves; wave w: g = w&1, rows rbase=(w>>1)*32 (2 mt of 16)
__global__ __launch_bounds__(512, 2) void t1_gemm_kernel(
    const float* __restrict__ x, const float* __restrict__ bias,
    const _Float16* __restrict__ wpk_hi, const float* __restrict__ cb,
    float* __restrict__ out, int* __restrict__ k_idx,
    int* __restrict__ q1g0, int* __restrict__ q1g1, int* __restrict__ qc,
    float* __restrict__ ws_avgp, float* __restrict__ hist) {
  __shared__ alignas(16) _Float16 xs[128][40];     // 10 KB
  __shared__ alignas(16) _Float16 wlds[40 * 512];  // 40 KB (one ks of B-frags)
  __shared__ int rowk[128][2];                     // 1 KB

  const int t = threadIdx.x;
  const int wave = t >> 6, lane = t & 63;
  const int quad = lane >> 4, l15 = lane & 15;
  const int row0 = blockIdx.x * 128;
  const int g = wave & 1;
  const int rbase = (wave >> 1) * 32;

  const int sr = t >> 2;           // staging row 0..127
  const int sk = (t & 3) * 8;      // k offset 0,8,16,24

  f32x4 acc[2][20];
#pragma unroll
  for (int mt = 0; mt < 2; ++mt)
#pragma unroll
    for (int nt = 0; nt < 20; ++nt) acc[mt][nt] = (f32x4)0.f;

  const float4* xb4 = (const float4*)x + (size_t)(row0 + sr) * 128 + (sk >> 2);
  const float4* wsrc4 = (const float4*)wpk_hi;  // frag-packed, ks-major

  // preload ks=0
  float4 va = xb4[0], vb = xb4[1];
  float4 wreg[5];
#pragma unroll
  for (int j = 0; j < 5; ++j) wreg[j] = wsrc4[j * 512 + t];

#pragma unroll 1
  for (int ks = 0; ks < 16; ++ks) {
    // ---- stage phase: x (converted) + W into LDS ----
    half8 hh;
    float vv[8] = {va.x, va.y, va.z, va.w, vb.x, vb.y, vb.z, vb.w};
#pragma unroll
    for (int j = 0; j < 8; ++j) hh[j] = (_Float16)vv[j];
    *(half8*)&xs[sr][sk] = hh;
#pragma unroll
    for (int j = 0; j < 5; ++j)
      *(float4*)&wlds[(j * 512 + t) * 8] = wreg[j];
    __syncthreads();  // staging visible

    // prefetch next ks (registers; overlaps compute)
    if (ks < 15) {
      va = xb4[(ks + 1) * 8];
      vb = xb4[(ks + 1) * 8 + 1];
#pragma unroll
      for (int j = 0; j < 5; ++j)
        wreg[j] = wsrc4[(size_t)(ks + 1) * 2560 + j * 512 + t];
    }

    half8 a0 = *(const half8*)&xs[rbase + l15][quad * 8];
    half8 a1 = *(const half8*)&xs[rbase + 16 + l15][quad * 8];
#pragma unroll
    for (int nt = 0; nt < 20; ++nt) {
      half8 bb = *(const half8*)&wlds[((g * 20 + nt) * 512 + lane * 8)];
      acc[0][nt] = __builtin_amdgcn_mfma_f32_16x16x32_f16(a0, bb, acc[0][nt], 0, 0, 0);
      acc[1][nt] = __builtin_amdgcn_mfma_f32_16x16x32_f16(a1, bb, acc[1][nt], 0, 0, 0);
    }
    __syncthreads();  // all reads done before next stage overwrites
  }

  // bias
#pragma unroll
  for (int nt = 0; nt < 20; ++nt) {
    float bb = bias[g * VDIM + nt * 16 + l15];
#pragma unroll
    for (int mt = 0; mt < 2; ++mt) {
      acc[mt][nt][0] += bb; acc[mt][nt][1] += bb;
      acc[mt][nt][2] += bb; acc[mt][nt][3] += bb;
    }
  }

  // ---- epilogue: top2/argmax + softmax partials + provisional k ----
  int* qg = (g == 0) ? q1g0 : q1g1;
  float pp[20];
#pragma unroll
  for (int nt = 0; nt < 20; ++nt) pp[nt] = 0.f;

#pragma unroll
  for (int mt = 0; mt < 2; ++mt) {
#pragma unroll
    for (int reg = 0; reg < 4; ++reg) {
      float m1 = -1e30f, m2 = -1e30f;
      int i1 = 0;
#pragma unroll
      for (int nt = 0; nt < 20; ++nt) {
        float v = acc[mt][nt][reg];
        int ci = nt * 16 + l15;
        if (v > m1) { m2 = m1; m1 = v; i1 = ci; }
        else if (v > m2) m2 = v;
      }
#pragma unroll
      for (int off = 1; off <= 8; off <<= 1) {
        float om1 = __shfl_xor(m1, off);
        int oi1 = __shfl_xor(i1, off);
        float om2 = __shfl_xor(m2, off);
        if (om1 > m1 || (om1 == m1 && oi1 < i1)) {
          m2 = fmaxf(m1, om2); m1 = om1; i1 = oi1;
        } else {
          m2 = fmaxf(m2, om1);
        }
      }
      float z = 0.f;
#pragma unroll
      for (int nt = 0; nt < 20; ++nt) z += __expf(acc[mt][nt][reg] - m1);
#pragma unroll
      for (int off = 1; off <= 8; off <<= 1) z += __shfl_xor(z, off);
      float rz = 1.f / z;
#pragma unroll
      for (int nt = 0; nt < 20; ++nt)
        pp[nt] += __expf(acc[mt][nt][reg] - m1) * rz;

      if (l15 == 0) {
        int glocal = rbase + mt * 16 + quad * 4 + reg;
        int grow = row0 + glocal;
        rowk[glocal][g] = i1;
        k_idx[grow * 2 + g] = i1;
        atomicAdd(&hist[g * VDIM + i1], 1.f);
        if (m1 - m2 < TAU1) {
          int qi = atomicAdd(&qc[g], 1);
          if (qi < Q1CAP) qg[qi] = grow;
        }
      }
    }
  }
#pragma unroll
  for (int nt = 0; nt < 20; ++nt) {
    pp[nt] += __shfl_xor(pp[nt], 16);
    pp[nt] += __shfl_xor(pp[nt], 32);
  }
  if (quad == 0) {
    float* dst = ws_avgp + (size_t)(blockIdx.x & (NREP - 1)) * MDIM + g * VDIM + l15;
#pragma unroll
    for (int nt = 0; nt < 20; ++nt) atomicAdd(dst + nt * 16, pp[nt]);
  }

  // ---- fused gather-write: out rows from rowk ----
  __syncthreads();
  const float4* cb4 = (const float4*)cb;
  float4* out4 = (float4*)out;
#pragma unroll
  for (int it = 0; it < 16; ++it) {
    int i = it * 512 + t;         // 8192 float4 slots = 128 rows * 64
    int row = i >> 6, f4 = i & 63;
    int gg = f4 >> 5, d4 = f4 & 31;
    int kk = rowk[row][gg];
    out4[(size_t)(row0 + row) * 64 + f4] = cb4[(size_t)(gg * VDIM + kk) * 32 + d4];
  }
}

// ---- tier-2: f16x3 recompute of flagged entries; fix-forward out/hist ----
__global__ __launch_bounds__(256) void t2_kernel(
    const float* __restrict__ x, const float* __restrict__ bias,
    const _Float16* __restrict__ wpk_hi, const _Float16* __restrict__ wpk_lo,
    const int* __restrict__ q1g0, const int* __restrict__ q1g1,
    const int* __restrict__ qc, int* __restrict__ k_idx,
    int* __restrict__ q2, int* __restrict__ qc2,
    const float* __restrict__ cb, float* __restrict__ out,
    float* __restrict__ hist) {
  __shared__ int sh_row[4][16];
  __shared__ int sh_k[4][16];
  const int t = threadIdx.x;
  const int wave = t >> 6, lane = t & 63;
  const int quad = lane >> 4, l15 = lane & 15;
  const float4* cb4 = (const float4*)cb;
  float4* out4 = (float4*)out;

  for (int g = 0; g < 2; ++g) {
    const int* queue = (g == 0) ? q1g0 : q1g1;
    int n = qc[g];
    if (n > Q1CAP) n = Q1CAP;

    for (int tbase0 = blockIdx.x * 64; tbase0 < n; tbase0 += gridDim.x * 64) {
      int tbase = tbase0 + wave * 16;
      int e = tbase + l15;
      int row = (e < n) ? queue[e] : 0;

      f32x4 acc[20];
#pragma unroll
      for (int nt = 0; nt < 20; ++nt) acc[nt] = (f32x4)0.f;

      const float4* xp = (const float4*)x + (size_t)row * 128 + quad * 2;
#pragma unroll 1
      for (int ks = 0; ks < 16; ++ks) {
        float4 va = xp[ks * 8], vb = xp[ks * 8 + 1];
        half8 ah, al;
        float vv[8] = {va.x, va.y, va.z, va.w, vb.x, vb.y, vb.z, vb.w};
#pragma unroll
        for (int j = 0; j < 8; ++j) {
          ah[j] = (_Float16)vv[j];
          al[j] = (_Float16)(vv[j] - (float)ah[j]);
        }
        const _Float16* bp = wpk_hi + ((size_t)(ks * 2 + g) * 20) * 512 + lane * 8;
        const _Float16* bpl = wpk_lo + ((size_t)(ks * 2 + g) * 20) * 512 + lane * 8;
#pragma unroll
        for (int nt = 0; nt < 20; ++nt) {
          half8 bh = *(const half8*)(bp + (size_t)nt * 512);
          half8 bl = *(const half8*)(bpl + (size_t)nt * 512);
          acc[nt] = __builtin_amdgcn_mfma_f32_16x16x32_f16(ah, bh, acc[nt], 0, 0, 0);
          acc[nt] = __builtin_amdgcn_mfma_f32_16x16x32_f16(ah, bl, acc[nt], 0, 0, 0);
          acc[nt] = __builtin_amdgcn_mfma_f32_16x16x32_f16(al, bh, acc[nt], 0, 0, 0);
        }
      }
#pragma unroll
      for (int reg = 0; reg < 4; ++reg) {
        float m1 = -1e30f, m2 = -1e30f;
        int i1 = 0;
#pragma unroll
        for (int nt = 0; nt < 20; ++nt) {
          float v = acc[nt][reg] + bias[g * VDIM + nt * 16 + l15];
          int ci = nt * 16 + l15;
          if (v > m1) { m2 = m1; m1 = v; i1 = ci; }
          else if (v > m2) m2 = v;
        }
#pragma unroll
        for (int off = 1; off <= 8; off <<= 1) {
          float om1 = __shfl_xor(m1, off);
          int oi1 = __shfl_xor(i1, off);
          float om2 = __shfl_xor(m2, off);
          if (om1 > m1 || (om1 == m1 && oi1 < i1)) {
            m2 = fmaxf(m1, om2); m1 = om1; i1 = oi1;
          } else {
            m2 = fmaxf(m2, om1);
          }
        }
        if (l15 == 0) {
          int ew = tbase + quad * 4 + reg;
          int ent = quad * 4 + reg;
          if (ew < n) {
            int rw = queue[ew];
            int kold = k_idx[rw * 2 + g];
            if (i1 != kold) {
              atomicAdd(&hist[g * VDIM + kold], -1.f);
              atomicAdd(&hist[g * VDIM + i1], 1.f);
              k_idx[rw * 2 + g] = i1;
            }
            sh_row[wave][ent] = rw;
            sh_k[wave][ent] = i1;
            if (m1 - m2 < TAU2) {
              int qi = atomicAdd(qc2, 1);
              if (qi < Q2CAP) q2[qi] = rw * 2 + g;
            }
          } else {
            sh_row[wave][ent] = -1;
          }
        }
      }
      // wave-lockstep: LDS writes above visible to this wave's lanes
#pragma unroll
      for (int j = 0; j < 8; ++j) {
        int slot = j * 64 + lane;     // 512 slots = 16 ents * 32 float4
        int ent = slot >> 5, d4 = slot & 31;
        int rr = sh_row[wave][ent];
        if (rr >= 0) {
          int kk = sh_k[wave][ent];
          out4[(size_t)rr * 64 + g * 32 + d4] = cb4[(size_t)(g * VDIM + kk) * 32 + d4];
        }
      }
    }
  }
}

// ---- tier-3: exact f64 recompute; fix-forward out/hist ----
__global__ __launch_bounds__(256) void fixup_kernel(
    const float* __restrict__ x, const float* __restrict__ W,
    const float* __restrict__ bias, const int* __restrict__ queue,
    const int* __restrict__ qcount, const int* __restrict__ k_idx,
    const float* __restrict__ cb, float* __restrict__ out,
    float* __restrict__ hist) {
  __shared__ float xrow[CDIM];
  __shared__ double sval[256];
  __shared__ int sidx[256];
  __shared__ int sk3;
  const int t = threadIdx.x;
  int n = *qcount;
  if (n > Q2CAP) n = Q2CAP;
  for (int i = blockIdx.x; i < n; i += gridDim.x) {
    int e = queue[i];
    int row = e >> 1, g = e & 1;
    __syncthreads();
    xrow[t] = x[(size_t)row * CDIM + t];
    xrow[t + 256] = x[(size_t)row * CDIM + 256 + t];
    __syncthreads();
    double bv = -1e300;
    int bi = 0;
    for (int c = t; c < VDIM; c += 256) {
      const float* wp = W + g * VDIM + c;
      double a0 = 0, a1 = 0, a2 = 0, a3 = 0;
      for (int k = 0; k < CDIM; k += 4) {
        a0 = fma((double)xrow[k],     (double)wp[(size_t)k * MDIM], a0);
        a1 = fma((double)xrow[k + 1], (double)wp[(size_t)(k + 1) * MDIM], a1);
        a2 = fma((double)xrow[k + 2], (double)wp[(size_t)(k + 2) * MDIM], a2);
        a3 = fma((double)xrow[k + 3], (double)wp[(size_t)(k + 3) * MDIM], a3);
      }
      double a = ((a0 + a1) + (a2 + a3)) + (double)bias[g * VDIM + c];
      if (a > bv) { bv = a; bi = c; }
    }
    sval[t] = bv; sidx[t] = bi;
    __syncthreads();
    for (int s = 128; s > 0; s >>= 1) {
      if (t < s) {
        if (sval[t + s] > sval[t] ||
            (sval[t + s] == sval[t] && sidx[t + s] < sidx[t])) {
          sval[t] = sval[t + s]; sidx[t] = sidx[t + s];
        }
      }
      __syncthreads();
    }
    if (t == 0) {
      int k3 = sidx[0];
      int kold = k_idx[row * 2 + g];
      if (k3 != kold) {
        atomicAdd(&hist[g * VDIM + kold], -1.f);
        atomicAdd(&hist[g * VDIM + k3], 1.f);
      }
      sk3 = k3;
    }
    __syncthreads();
    if (t < 32) {
      const float4* cb4 = (const float4*)cb;
      float4* out4 = (float4*)out;
      out4[(size_t)row * 64 + g * 32 + t] = cb4[(size_t)(g * VDIM + sk3) * 32 + t];
    }
  }
}

__global__ __launch_bounds__(256) void gvq_finalize_kernel(
    const float* __restrict__ ws_avgp, const float* __restrict__ ws_hist,
    float* __restrict__ out) {
  __shared__ double red[256];
  const int t = threadIdx.x;
  double pp[2] = {0.0, 0.0}, hp[2] = {0.0, 0.0};
  for (int c = t; c < MDIM; c += 256) {
    double s = 0.0;
    for (int rep = 0; rep < NREP; ++rep) s += (double)ws_avgp[rep * MDIM + c];
    double avg = s / (double)NROWS;
    double hard = (double)ws_hist[c] / (double)NROWS;
    int g = (c < VDIM) ? 0 : 1;
    pp[g] += avg * log(avg + 1e-7);
    hp[g] += hard * log(hard + 1e-7);
  }
  double vals[4] = {pp[0], pp[1], hp[0], hp[1]};
  double res[4];
  for (int i = 0; i < 4; ++i) {
    red[t] = vals[i];
    __syncthreads();
    for (int s = 128; s > 0; s >>= 1) {
      if (t < s) red[t] += red[t + s];
      __syncthreads();
    }
    res[i] = red[0];
    __syncthreads();
  }
  if (t == 0) {
    out[OUTN]     = (float)(exp(-res[2]) + exp(-res[3]));
    out[OUTN + 1] = (float)(exp(-res[0]) + exp(-res[1]));
  }
}

// ================= fallback (round-1 verified f64 path) =================
__global__ __launch_bounds__(256) void zero_ws_kernel(float* ws, int n) {
  int i = blockIdx.x * 256 + threadIdx.x;
  if (i < n) ws[i] = 0.f;
}

__global__ __launch_bounds__(256) void fb_main_kernel(
    const float* __restrict__ x, const float* __restrict__ W,
    const float* __restrict__ b, const float* __restrict__ cb,
    float* __restrict__ out, float* __restrict__ ws_avgp,
    float* __restrict__ ws_hist) {
  __shared__ float xs[8][CDIM];
  __shared__ float lg[8][MDIM];
  __shared__ float avgp[MDIM];
  __shared__ int rowk[8][2];
  const int t = threadIdx.x;
  const int row0 = blockIdx.x * 8;
  avgp[t] = 0.f; avgp[t + 256] = 0.f;
  if (t < 128) avgp[t + 512] = 0.f;
  const float4* x4 = (const float4*)(x + (size_t)row0 * CDIM);
  float4* xs4 = (float4*)&xs[0][0];
#pragma unroll
  for (int i = 0; i < 4; ++i) xs4[t + i * 256] = x4[t + i * 256];
  __syncthreads();
  const int c0 = t, c1 = t + 256;
  const int c2 = (t < 128) ? (t + 512) : 639;
  double a0[8], a1[8], a2[8];
#pragma unroll
  for (int r = 0; r < 8; ++r) { a0[r] = 0.0; a1[r] = 0.0; a2[r] = 0.0; }
  const float* Wk = W;
  for (int k = 0; k < CDIM; ++k) {
    double w0 = (double)Wk[c0], w1 = (double)Wk[c1], w2 = (double)Wk[c2];
#pragma unroll
    for (int r = 0; r < 8; ++r) {
      double xv = (double)xs[r][k];
      a0[r] = fma(xv, w0, a0[r]);
      a1[r] = fma(xv, w1, a1[r]);
      a2[r] = fma(xv, w2, a2[r]);
    }
    Wk += MDIM;
  }
#pragma unroll
  for (int r = 0; r < 8; ++r) {
    lg[r][c0] = (float)(a0[r] + (double)b[c0]);
    lg[r][c1] = (float)(a1[r] + (double)b[c1]);
    if (t < 128) lg[r][c2] = (float)(a2[r] + (double)b[c2]);
  }
  __syncthreads();
  const int wave = t >> 6, lane = t & 63;
  for (int r = wave; r < 8; r += 4) {
    float m0 = -1e30f, m1 = -1e30f;
    int i0 = 0, i1 = VDIM;
    float e0v[5], e1v[5];
#pragma unroll
    for (int j = 0; j < 5; ++j) {
      int ca = lane + j * 64;
      float v = lg[r][ca]; e0v[j] = v;
      if (v > m0) { m0 = v; i0 = ca; }
      float v2 = lg[r][VDIM + ca]; e1v[j] = v2;
      if (v2 > m1) { m1 = v2; i1 = VDIM + ca; }
    }
#pragma unroll
    for (int off = 32; off > 0; off >>= 1) {
      float om = __shfl_xor(m0, off); int oi = __shfl_xor(i0, off);
      if (om > m0 || (om == m0 && oi < i0)) { m0 = om; i0 = oi; }
      om = __shfl_xor(m1, off); oi = __shfl_xor(i1, off);
      if (om > m1 || (om == m1 && oi < i1)) { m1 = om; i1 = oi; }
    }
    float z0 = 0.f, z1 = 0.f;
#pragma unroll
    for (int j = 0; j < 5; ++j) {
      e0v[j] = expf(e0v[j] - m0); z0 += e0v[j];
      e1v[j] = expf(e1v[j] - m1); z1 += e1v[j];
    }
#pragma unroll
    for (int off = 32; off > 0; off >>= 1) {
      z0 += __shfl_xor(z0, off); z1 += __shfl_xor(z1, off);
    }
    float r0 = 1.f / z0, r1 = 1.f / z1;
#pragma unroll
    for (int j = 0; j < 5; ++j) {
      atomicAdd(&avgp[lane + j * 64], e0v[j] * r0);
      atomicAdd(&avgp[VDIM + lane + j * 64], e1v[j] * r1);
    }
    if (lane == 0) {
      rowk[r][0] = i0; rowk[r][1] = i1 - VDIM;
      atomicAdd(&ws_hist[i0], 1.f);
      atomicAdd(&ws_hist[i1], 1.f);
    }
  }
  __syncthreads();
  const int g = t >> 7, dd = t & 127;
#pragma unroll
  for (int r = 0; r < 8; ++r) {
    int kk = rowk[r][g];
    out[(size_t)(row0 + r) * 256 + t] = cb[((size_t)(g * VDIM + kk)) * DDIM + dd];
  }
  float* dst = ws_avgp + (size_t)(blockIdx.x & 31) * MDIM;
  atomicAdd(&dst[t], avgp[t]);
  atomicAdd(&dst[t + 256], avgp[t + 256]);
  if (t < 128) atomicAdd(&dst[t + 512], avgp[t + 512]);
}

extern "C" void kernel_launch(void* const* d_in, const int* in_sizes, int n_in,
                              void* d_out, int out_size, void* d_ws, size_t ws_size,
                              hipStream_t stream) {
  const float* x  = (const float*)d_in[0];
  const float* W  = (const float*)d_in[1];
  const float* b  = (const float*)d_in[2];
  const float* cb = (const float*)d_in[3];
  float* out = (float*)d_out;
  char* ws = (char*)d_ws;

  if (ws_size >= (size_t)WS_NEEDED) {
    _Float16* wpk_hi = (_Float16*)(ws + WPK_HI_OFF);
    _Float16* wpk_lo = (_Float16*)(ws + WPK_LO_OFF);
    int* k_idx = (int*)(ws + KIDX_OFF);
    int* q1g0 = (int*)(ws + Q1G0_OFF);
    int* q1g1 = (int*)(ws + Q1G1_OFF);
    int* q2   = (int*)(ws + Q2_OFF);
    int* qc   = (int*)(ws + CNT_OFF);
    float* avgp = (float*)(ws + AVGP_OFF);
    float* hist = (float*)(ws + HIST_OFF);

    prep_kernel<<<160 + ZBLOCKS, 256, 0, stream>>>(W, wpk_hi, wpk_lo,
                                                   (float*)(ws + CNT_OFF));
    t1_gemm_kernel<<<NROWS / 128, 512, 0, stream>>>(x, b, wpk_hi, cb, out,
                                                    k_idx, q1g0, q1g1, qc,
                                                    avgp, hist);
    t2_kernel<<<128, 256, 0, stream>>>(x, b, wpk_hi, wpk_lo, q1g0, q1g1, qc,
                                       k_idx, q2, qc + 2, cb, out, hist);
    fixup_kernel<<<128, 256, 0, stream>>>(x, W, b, q2, qc + 2, k_idx, cb, out,
                                          hist);
    gvq_finalize_kernel<<<1, 256, 0, stream>>>(avgp, hist, out);
  } else {
    float* ws_avgp = (float*)ws;
    float* ws_hist = (float*)ws + NREP * MDIM;
    const int zn = NREP * MDIM + MDIM;
    zero_ws_kernel<<<(zn + 255) / 256, 256, 0, stream>>>((float*)ws, zn);
    fb_main_kernel<<<NROWS / 8, 256, 0, stream>>>(x, W, b, cb, out, ws_avgp, ws_hist);
    gvq_finalize_kernel<<<1, 256, 0, stream>>>(ws_avgp, ws_hist, out);
  }
}